// Round 1
// 2914.278 us; speedup vs baseline: 1.0558x; 1.0558x over previous
//
#include <hip/hip_runtime.h>
#include <cstdint>

// Problem dims
#define VOCAB  32000
#define EMB    256
#define HID    512
#define TLEN   64
#define BATCH  64
#define G4     2048          // 4*HID
#define OUT_LOGITS ((size_t)BATCH * TLEN * VOCAB)   // 131,072,000
#define BTV    ((size_t)TLEN * VOCAB)               // 2,048,000 (stride per b in out)

typedef short s16x8 __attribute__((ext_vector_type(8)));   // 8 bf16 operand frag
typedef float f32x4 __attribute__((ext_vector_type(4)));   // 4 fp32 acc frag

// ---- workspace layout (bytes) ----
#define WS_FCW_HI  0ull
#define WS_FCW_LO  32768000ull
#define WS_WIH_HI  65536000ull
#define WS_WIH_LO  66584576ull
#define WS_WHH_HI  67633152ull
#define WS_WHH_LO  69730304ull
#define WS_BIAS    71827456ull
#define WS_CBUF    71835648ull
#define WS_HBUF    71966720ull
#define WS_HHI     72097792ull   // [65][64][512] bf16 (slot s = h input of step s; slot t+1 = h after cell t)
#define WS_HLO     76357632ull   // [65][64][512] bf16
#define WS_AMAX    80617472ull   // [64][64] u64
#define WS_NEEDED  80650240ull

__device__ __forceinline__ unsigned bf16_hi_bits(float x) {
    unsigned u = __float_as_uint(x);
    return (u + 0x7FFFu + ((u >> 16) & 1u)) >> 16;   // RNE truncation to bf16
}
__device__ __forceinline__ float bf16_bits_to_f(unsigned b) {
    return __uint_as_float(b << 16);
}
// order-preserving float->uint key (bigger float => bigger key)
__device__ __forceinline__ unsigned fkey(float x) {
    unsigned u = __float_as_uint(x);
    return (u & 0x80000000u) ? ~u : (u | 0x80000000u);
}

// ---------------- precompute: bf16 hi/lo splits, bias fuse, state init ----------------
__global__ __launch_bounds__(256) void k_pre(
    const float* __restrict__ fcw, const float* __restrict__ wih, const float* __restrict__ whh,
    const float* __restrict__ bih, const float* __restrict__ bhh,
    const float* __restrict__ ench, const float* __restrict__ encc,
    unsigned short* fcw_hi, unsigned short* fcw_lo,
    unsigned short* wih_hi, unsigned short* wih_lo,
    unsigned short* whh_hi, unsigned short* whh_lo,
    float* bias, float* c_buf, unsigned short* hhi, unsigned short* hlo,
    unsigned long long* amax)
{
    size_t g = (size_t)blockIdx.x * 256 + threadIdx.x;
    size_t s = (size_t)gridDim.x * 256;
    for (size_t i = g; i < (size_t)VOCAB * HID; i += s) {
        float x = fcw[i]; unsigned hb = bf16_hi_bits(x);
        fcw_hi[i] = (unsigned short)hb;
        fcw_lo[i] = (unsigned short)bf16_hi_bits(x - bf16_bits_to_f(hb));
    }
    for (size_t i = g; i < (size_t)G4 * EMB; i += s) {
        float x = wih[i]; unsigned hb = bf16_hi_bits(x);
        wih_hi[i] = (unsigned short)hb;
        wih_lo[i] = (unsigned short)bf16_hi_bits(x - bf16_bits_to_f(hb));
    }
    for (size_t i = g; i < (size_t)G4 * HID; i += s) {
        float x = whh[i]; unsigned hb = bf16_hi_bits(x);
        whh_hi[i] = (unsigned short)hb;
        whh_lo[i] = (unsigned short)bf16_hi_bits(x - bf16_bits_to_f(hb));
    }
    for (size_t i = g; i < G4; i += s) bias[i] = bih[i] + bhh[i];
    for (size_t i = g; i < (size_t)BATCH * HID; i += s) {
        c_buf[i] = encc[i];
        float x = ench[i]; unsigned hb = bf16_hi_bits(x);
        hhi[i] = (unsigned short)hb;                 // slot 0 = encoder h (input of step 0)
        hlo[i] = (unsigned short)bf16_hi_bits(x - bf16_bits_to_f(hb));
    }
    for (size_t i = g; i < (size_t)TLEN * BATCH; i += s) amax[i] = 0ull;
}

// ---------------- phase 1: token select + gates GEMM (bf16x3 MFMA) + LSTM cell ----------------
// grid: 128 blocks = 32 j-tiles x 4 b-tiles; 256 threads = 4 waves, wave w = gate type w (i,f,g,o)
// reads h slot t, writes h slot t+1
__global__ __launch_bounds__(256) void k_cell(
    const float* __restrict__ emb,
    const unsigned short* __restrict__ wih_hi, const unsigned short* __restrict__ wih_lo,
    const unsigned short* __restrict__ whh_hi, const unsigned short* __restrict__ whh_lo,
    const float* __restrict__ bias,
    const int* __restrict__ target, const int* __restrict__ tf_mask,
    const unsigned long long* __restrict__ amax,
    float* c_buf, float* h_buf, unsigned short* hhi, unsigned short* hlo, int t)
{
    __shared__ __align__(16) unsigned short xs_hi[16 * 264];
    __shared__ __align__(16) unsigned short xs_lo[16 * 264];
    __shared__ float gbuf[4 * 16 * 16];
    __shared__ int tok_s[16];

    const int tid = threadIdx.x;
    const int jt = blockIdx.x >> 2;          // 0..31
    const int b0 = (blockIdx.x & 3) * 16;    // batch tile base

    // ---- resolve input tokens for this block's 16 batch rows ----
    if (tid < 16) {
        int b = b0 + tid;
        int tok = 0;
        if (t > 0) {
            if (tf_mask[t - 1] > 0) tok = target[b * TLEN + (t - 1)];
            else {
                unsigned long long k = amax[(size_t)(t - 1) * BATCH + b];
                tok = (int)(~(unsigned)k);
            }
        }
        tok_s[tid] = tok;
    }
    __syncthreads();

    // ---- stage embedding rows split to bf16 hi/lo in LDS ----
    for (int i = tid; i < 16 * 32; i += 256) {
        int row = i >> 5, seg = i & 31;              // 8 elems per item
        const float* src = emb + (size_t)tok_s[row] * EMB + seg * 8;
        int dst = row * 264 + seg * 8;
        #pragma unroll
        for (int e = 0; e < 8; e++) {
            float x = src[e]; unsigned hb = bf16_hi_bits(x);
            xs_hi[dst + e] = (unsigned short)hb;
            xs_lo[dst + e] = (unsigned short)bf16_hi_bits(x - bf16_bits_to_f(hb));
        }
    }
    __syncthreads();

    const int w = tid >> 6, l = tid & 63, li = l & 15, q = l >> 4;
    const int row0 = w * HID + jt * 16;      // gate-row base in [0,2048)
    const unsigned short* hh = hhi + (size_t)t * BATCH * HID;
    const unsigned short* hl = hlo + (size_t)t * BATCH * HID;

    f32x4 acc = {0.f, 0.f, 0.f, 0.f};
    // K over embedding part (256)
    #pragma unroll
    for (int kc = 0; kc < 8; kc++) {
        int ka = kc * 32 + q * 8;
        s16x8 ah = *(const s16x8*)(wih_hi + (size_t)(row0 + li) * EMB + ka);
        s16x8 al = *(const s16x8*)(wih_lo + (size_t)(row0 + li) * EMB + ka);
        s16x8 bh = *(const s16x8*)(xs_hi + li * 264 + ka);
        s16x8 bl = *(const s16x8*)(xs_lo + li * 264 + ka);
        acc = __builtin_amdgcn_mfma_f32_16x16x32_bf16(ah, bh, acc, 0, 0, 0);
        acc = __builtin_amdgcn_mfma_f32_16x16x32_bf16(ah, bl, acc, 0, 0, 0);
        acc = __builtin_amdgcn_mfma_f32_16x16x32_bf16(al, bh, acc, 0, 0, 0);
    }
    // K over hidden part (512)
    #pragma unroll
    for (int kc = 0; kc < 16; kc++) {
        int ka = kc * 32 + q * 8;
        s16x8 ah = *(const s16x8*)(whh_hi + (size_t)(row0 + li) * HID + ka);
        s16x8 al = *(const s16x8*)(whh_lo + (size_t)(row0 + li) * HID + ka);
        s16x8 bh = *(const s16x8*)(hh + (size_t)(b0 + li) * HID + ka);
        s16x8 bl = *(const s16x8*)(hl + (size_t)(b0 + li) * HID + ka);
        acc = __builtin_amdgcn_mfma_f32_16x16x32_bf16(ah, bh, acc, 0, 0, 0);
        acc = __builtin_amdgcn_mfma_f32_16x16x32_bf16(ah, bl, acc, 0, 0, 0);
        acc = __builtin_amdgcn_mfma_f32_16x16x32_bf16(al, bh, acc, 0, 0, 0);
    }
    // D layout: row m = q*4+r, col = li
    #pragma unroll
    for (int r = 0; r < 4; r++) {
        int m = q * 4 + r;
        gbuf[w * 256 + m * 16 + li] = acc[r] + bias[row0 + m];
    }
    __syncthreads();

    // ---- LSTM cell update: thread -> (j_local, b_local) ----
    {
        int jl = tid >> 4, bl = tid & 15;
        float gi = gbuf[0 * 256 + jl * 16 + bl];
        float gf = gbuf[1 * 256 + jl * 16 + bl];
        float gg = gbuf[2 * 256 + jl * 16 + bl];
        float go = gbuf[3 * 256 + jl * 16 + bl];
        int j = jt * 16 + jl, b = b0 + bl;
        size_t off = (size_t)b * HID + j;
        float ii = 1.f / (1.f + expf(-gi));
        float ff = 1.f / (1.f + expf(-gf));
        float oo = 1.f / (1.f + expf(-go));
        float c_new = ff * c_buf[off] + ii * tanhf(gg);
        float h_new = oo * tanhf(c_new);
        c_buf[off] = c_new;
        h_buf[off] = h_new;
        unsigned hb = bf16_hi_bits(h_new);
        size_t woff = (size_t)(t + 1) * BATCH * HID + off;   // slot t+1
        hhi[woff] = (unsigned short)hb;
        hlo[woff] = (unsigned short)bf16_hi_bits(h_new - bf16_bits_to_f(hb));
    }
}

// ---------------- phase 2 (serial path): argmax only, no logit store ----------------
// Same verified structure as the old k_logits minus the output write.
// Whole grid exits immediately on teacher-forced steps.
// grid: 500 blocks x 64 vocab rows; 256 threads = 4 waves, wave w = v-tile w; loops 4 b-tiles
__global__ __launch_bounds__(256) void k_argmax(
    const unsigned short* __restrict__ fcw_hi, const unsigned short* __restrict__ fcw_lo,
    const unsigned short* __restrict__ hhi, const unsigned short* __restrict__ hlo,
    const float* __restrict__ fcb, const int* __restrict__ tf_mask,
    unsigned long long* __restrict__ amax_t, int t)
{
    if (tf_mask[t] > 0) return;              // teacher forcing: greedy token unused

    __shared__ __align__(16) char smem[34816];
    unsigned short* sBh = (unsigned short*)smem;              // [64][136] bf16 (padded)
    unsigned short* sBl = (unsigned short*)(smem + 17408);
    float* sOut = (float*)smem;                               // [64][68] f32 (reused after K-loop)

    const int tid = threadIdx.x;
    const int v0 = blockIdx.x * 64;
    const int w = tid >> 6, l = tid & 63, li = l & 15, q = l >> 4;
    const unsigned short* hh = hhi + (size_t)(t + 1) * BATCH * HID;   // h after cell t
    const unsigned short* hl = hlo + (size_t)(t + 1) * BATCH * HID;

    f32x4 acc[4] = {{0,0,0,0},{0,0,0,0},{0,0,0,0},{0,0,0,0}};

    for (int kit = 0; kit < 4; kit++) {
        int kbase = kit * 128;
        __syncthreads();
        // stage h hi/lo chunk [64 b][128 k] into LDS (pad rows to 136)
        for (int i = tid; i < 1024; i += 256) {
            int row = i >> 4, seg = i & 15;
            *(s16x8*)(sBh + row * 136 + seg * 8) = *(const s16x8*)(hh + (size_t)row * HID + kbase + seg * 8);
            *(s16x8*)(sBl + row * 136 + seg * 8) = *(const s16x8*)(hl + (size_t)row * HID + kbase + seg * 8);
        }
        __syncthreads();
        #pragma unroll
        for (int kc = 0; kc < 4; kc++) {
            int ka = kbase + kc * 32 + q * 8;    // global k (A)
            int kl = kc * 32 + q * 8;            // local k (B in LDS)
            s16x8 ah = *(const s16x8*)(fcw_hi + (size_t)(v0 + w * 16 + li) * HID + ka);
            s16x8 al = *(const s16x8*)(fcw_lo + (size_t)(v0 + w * 16 + li) * HID + ka);
            #pragma unroll
            for (int bt = 0; bt < 4; bt++) {
                s16x8 bh = *(const s16x8*)(sBh + (bt * 16 + li) * 136 + kl);
                s16x8 bl = *(const s16x8*)(sBl + (bt * 16 + li) * 136 + kl);
                acc[bt] = __builtin_amdgcn_mfma_f32_16x16x32_bf16(ah, bh, acc[bt], 0, 0, 0);
                acc[bt] = __builtin_amdgcn_mfma_f32_16x16x32_bf16(ah, bl, acc[bt], 0, 0, 0);
                acc[bt] = __builtin_amdgcn_mfma_f32_16x16x32_bf16(al, bh, acc[bt], 0, 0, 0);
            }
        }
    }
    __syncthreads();   // all waves done with sB before aliasing as sOut

    // epilogue: bias add, transpose into LDS [b][v_local] (padded 68)
    #pragma unroll
    for (int bt = 0; bt < 4; bt++) {
        #pragma unroll
        for (int r = 0; r < 4; r++) {
            int vl = w * 16 + q * 4 + r;
            int b = bt * 16 + li;
            sOut[b * 68 + vl] = acc[bt][r] + fcb[v0 + vl];
        }
    }
    __syncthreads();

    // argmax: 4 threads per batch row scan 16 v each, pack (key<<32)|~v, shuffle-reduce, atomicMax
    {
        int b = tid >> 2, i4 = tid & 3;
        float best = -1e38f; int bidx = 0;
        #pragma unroll
        for (int e = 0; e < 16; e++) {
            int vl = i4 * 16 + e;
            float x = sOut[b * 68 + vl];
            if (x > best) { best = x; bidx = vl; }   // strict > keeps smallest index
        }
        unsigned long long pk = ((unsigned long long)fkey(best) << 32) | (unsigned)(~(unsigned)(v0 + bidx));
        unsigned long long o1 = __shfl_xor(pk, 1); if (o1 > pk) pk = o1;
        unsigned long long o2 = __shfl_xor(pk, 2); if (o2 > pk) pk = o2;
        if (i4 == 0) atomicMax(amax_t + b, pk);
    }
}

// ---------------- phase 3: batched logits GEMM for ALL steps ----------------
// M = 4096 (m = t*64 + b), N = 32000, K = 512. A = fcw rows (direct gather, 16/wave/nf),
// B = h rows staged in LDS with 16B-chunk XOR swizzle (conflict-free ds_read_b128).
// grid: 2000 blocks (bid = nt*16 + mt, nt-major so 16 consecutive blocks share the fcw panel);
// 512 threads = 8 waves (wm 0..1 x wn 0..3); wave = 128 m x 64 n; acc 8x4 frags.
// Accumulation order per element matches k_argmax: ascending 32-k chunks, products hh,hl,lh.
__global__ __launch_bounds__(512) void k_blogits(
    const unsigned short* __restrict__ fcw_hi, const unsigned short* __restrict__ fcw_lo,
    const unsigned short* __restrict__ hhi, const unsigned short* __restrict__ hlo,
    const float* __restrict__ fcb, float* __restrict__ out)
{
    __shared__ __align__(16) char smem[67584];
    unsigned short* sBh = (unsigned short*)smem;            // [256][64] bf16, swizzled
    unsigned short* sBl = (unsigned short*)(smem + 32768);
    float* sOut = (float*)smem;                             // [64][264] f32 (reuse)

    const int tid = threadIdx.x;
    const int mt = blockIdx.x & 15;          // 0..15 (256 m rows each)
    const int nt = blockIdx.x >> 4;          // 0..124 (256 v rows each)
    const int n0 = nt * 256;
    const int ww = tid >> 6, l = tid & 63, li = l & 15, q = l >> 4;
    const int wm = ww >> 2, wn = ww & 3;
    // m = t*64 + b  ->  h row = (t+1)*64 + b = m + 64 (contiguous in the slot array)
    const size_t hbase = ((size_t)mt * 256 + BATCH) * HID;

    f32x4 acc[8][4];
    #pragma unroll
    for (int i = 0; i < 8; i++)
        #pragma unroll
        for (int j = 0; j < 4; j++) acc[i][j] = (f32x4){0.f, 0.f, 0.f, 0.f};

    for (int kit = 0; kit < 8; kit++) {
        int kbase = kit * 64;
        __syncthreads();
        // stage B (h) [256 m][64 k] hi+lo; 16B chunk c8 XOR-swizzled by (row&7)
        #pragma unroll
        for (int i2 = 0; i2 < 4; i2++) {
            int idx = i2 * 512 + tid;        // 0..2047
            int row = idx >> 3, c8 = idx & 7;
            size_t src = hbase + (size_t)row * HID + kbase + c8 * 8;
            int dst = row * 64 + ((c8 ^ (row & 7)) << 3);
            *(s16x8*)(sBh + dst) = *(const s16x8*)(hhi + src);
            *(s16x8*)(sBl + dst) = *(const s16x8*)(hlo + src);
        }
        __syncthreads();
        #pragma unroll
        for (int kc = 0; kc < 2; kc++) {
            int ka = kbase + kc * 32 + q * 8;
            s16x8 ah[4], al[4];
            #pragma unroll
            for (int nf = 0; nf < 4; nf++) {
                size_t arow = (size_t)(n0 + wn * 64 + nf * 16 + li) * HID + ka;
                ah[nf] = *(const s16x8*)(fcw_hi + arow);
                al[nf] = *(const s16x8*)(fcw_lo + arow);
            }
            #pragma unroll
            for (int mf = 0; mf < 8; mf++) {
                int row = wm * 128 + mf * 16 + li;
                int ch = kc * 4 + q;
                int off = row * 64 + (((ch ^ (row & 7)) & 7) << 3);
                s16x8 bh = *(const s16x8*)(sBh + off);
                s16x8 bl = *(const s16x8*)(sBl + off);
                #pragma unroll
                for (int nf = 0; nf < 4; nf++) {
                    acc[mf][nf] = __builtin_amdgcn_mfma_f32_16x16x32_bf16(ah[nf], bh, acc[mf][nf], 0, 0, 0);
                    acc[mf][nf] = __builtin_amdgcn_mfma_f32_16x16x32_bf16(ah[nf], bl, acc[mf][nf], 0, 0, 0);
                    acc[mf][nf] = __builtin_amdgcn_mfma_f32_16x16x32_bf16(al[nf], bh, acc[mf][nf], 0, 0, 0);
                }
            }
        }
    }

    // epilogue: 4 rounds of 64 m-rows each; round rd -> t = mt*4 + rd, b = row within round
    for (int rd = 0; rd < 4; rd++) {
        __syncthreads();
        if (wm == (rd >> 1)) {
            #pragma unroll
            for (int mfi = 0; mfi < 4; mfi++) {
                int mf = (rd & 1) * 4 + mfi;
                int mrow = mf * 16 + li - (rd & 1) * 64;     // 0..63 within round
                #pragma unroll
                for (int nf = 0; nf < 4; nf++) {
                    #pragma unroll
                    for (int r = 0; r < 4; r++) {
                        int nl = wn * 64 + nf * 16 + q * 4 + r;
                        sOut[mrow * 264 + nl] = acc[mf][nf][r] + fcb[n0 + nl];
                    }
                }
            }
        }
        __syncthreads();
        int tglob = mt * 4 + rd;
        #pragma unroll
        for (int it = 0; it < 8; it++) {
            int idx = it * 512 + tid;        // 0..4095
            int row = idx >> 6, v4 = idx & 63;
            float4 val = *(const float4*)&sOut[row * 264 + v4 * 4];
            *(float4*)(out + (size_t)row * BTV + (size_t)tglob * VOCAB + n0 + v4 * 4) = val;
        }
    }
}

// ---------------- tail: copy final h, c to output ----------------
__global__ __launch_bounds__(256) void k_tail(const float* __restrict__ h_buf,
                                              const float* __restrict__ c_buf,
                                              float* __restrict__ out)
{
    int i = blockIdx.x * 256 + threadIdx.x;
    if (i < BATCH * HID) out[OUT_LOGITS + i] = h_buf[i];
    else                 out[OUT_LOGITS + i] = c_buf[i - BATCH * HID];
}

extern "C" void kernel_launch(void* const* d_in, const int* in_sizes, int n_in,
                              void* d_out, int out_size, void* d_ws, size_t ws_size,
                              hipStream_t stream) {
    const float* ench   = (const float*)d_in[0];
    const float* encc   = (const float*)d_in[1];
    const int*   target = (const int*)d_in[2];     // jnp.int64 materializes as int32 (JAX x64 off)
    const int*   tfmask = (const int*)d_in[3];
    const float* emb    = (const float*)d_in[4];
    const float* wih    = (const float*)d_in[5];
    const float* whh    = (const float*)d_in[6];
    const float* bih    = (const float*)d_in[7];
    const float* bhh    = (const float*)d_in[8];
    const float* fcw    = (const float*)d_in[9];
    const float* fcb    = (const float*)d_in[10];

    if (ws_size < WS_NEEDED) return;  // visible failure rather than corruption

    char* ws = (char*)d_ws;
    unsigned short* fcw_hi = (unsigned short*)(ws + WS_FCW_HI);
    unsigned short* fcw_lo = (unsigned short*)(ws + WS_FCW_LO);
    unsigned short* wih_hi = (unsigned short*)(ws + WS_WIH_HI);
    unsigned short* wih_lo = (unsigned short*)(ws + WS_WIH_LO);
    unsigned short* whh_hi = (unsigned short*)(ws + WS_WHH_HI);
    unsigned short* whh_lo = (unsigned short*)(ws + WS_WHH_LO);
    float* bias  = (float*)(ws + WS_BIAS);
    float* c_buf = (float*)(ws + WS_CBUF);
    float* h_buf = (float*)(ws + WS_HBUF);
    unsigned short* hhi = (unsigned short*)(ws + WS_HHI);
    unsigned short* hlo = (unsigned short*)(ws + WS_HLO);
    unsigned long long* amax = (unsigned long long*)(ws + WS_AMAX);
    float* out = (float*)d_out;

    k_pre<<<4096, 256, 0, stream>>>(fcw, wih, whh, bih, bhh, ench, encc,
                                    fcw_hi, fcw_lo, wih_hi, wih_lo, whh_hi, whh_lo,
                                    bias, c_buf, hhi, hlo, amax);

    // serial phase: cells + (conditionally early-exiting) argmax passes
    for (int t = 0; t < TLEN; t++) {
        k_cell<<<128, 256, 0, stream>>>(emb, wih_hi, wih_lo, whh_hi, whh_lo, bias,
                                        target, tfmask, amax, c_buf, h_buf, hhi, hlo, t);
        if (t < TLEN - 1)
            k_argmax<<<500, 256, 0, stream>>>(fcw_hi, fcw_lo, hhi, hlo, fcb, tfmask,
                                              amax + (size_t)t * BATCH, t);
    }

    // batched logits for all 64 steps (off the serial critical path)
    k_blogits<<<2000, 512, 0, stream>>>(fcw_hi, fcw_lo, hhi, hlo, fcb, out);

    k_tail<<<256, 256, 0, stream>>>(h_buf, c_buf, out);
}